// Round 11
// baseline (308.860 us; speedup 1.0000x reference)
//
#include <hip/hip_runtime.h>

#define NEG_SLOPE 0.2f
static constexpr int BLK = 256;
static constexpr int HS  = 16;   // head stride (ints) = one 64B line per node

typedef short bf16x8 __attribute__((ext_vector_type(8)));
typedef float f32x4  __attribute__((ext_vector_type(4)));
typedef unsigned short u16x8 __attribute__((ext_vector_type(8)));
typedef unsigned short u16x4 __attribute__((ext_vector_type(4)));

template<int NE> struct uvec_t;
template<> struct uvec_t<4>{ using T = u16x4; };
template<> struct uvec_t<8>{ using T = u16x8; };

static inline int cdiv(long a, long b){ return (int)((a + b - 1) / b); }

__device__ __forceinline__ unsigned short f2bf(float f){
    unsigned u = __float_as_uint(f);
    u += 0x7fff + ((u >> 16) & 1);          // RNE
    return (unsigned short)(u >> 16);
}
__device__ __forceinline__ float bf2f(unsigned short h){
    return __uint_as_float(((unsigned)h) << 16);
}

// ---------------- per-graph pointer bundle ----------------
struct GP {
    const int* src; const int* dst; const float* X;
    int* head;       // padded: head[n*HS]
    int2* pair; int* scan1b; int* bsum; int* rowptr; int* csrsrc;
    unsigned short* h1b; float* agg1; unsigned short* h2b;
    float *as1, *ad1, *as2, *ad2; float* outp;
};

// ---------------- device bodies ----------------
// LDS-staged MFMA GEMM: h = W_split x bf16(x). Block = 64 rows x CT*16 cols.
template<int CO, int CT, bool RELU_IN, bool BF16OUT>
__device__ __forceinline__ void gemm_dev(
    int bid, const float* __restrict__ X,
    const unsigned short* __restrict__ Wt_hi, const unsigned short* __restrict__ Wt_lo,
    const float* __restrict__ avs, const float* __restrict__ avd,
    void* __restrict__ Hout, float* __restrict__ as_out, float* __restrict__ ad_out,
    int N, unsigned short* smem)
{
    constexpr int CHUNKS = CO / (CT * 16);
    constexpr int HWB = CT * 4096;
    int ch, rtb;
    if (CHUNKS == 1){ ch = 0; rtb = bid; } else { ch = bid & 1; rtb = bid >> 1; }
    int c0 = ch * (CT * 16);

    {
        const char* srch = (const char*)(Wt_hi + (size_t)c0 * 128);
        const char* srcl = (const char*)(Wt_lo + (size_t)c0 * 128);
        #pragma unroll
        for (int it = 0; it < CT * 2; ++it){
            int o = (it * 256 + (int)threadIdx.x) * 16;
            const char* sp = (o < HWB) ? (srch + o) : (srcl + (o - HWB));
            u16x8 v = *(const u16x8*)sp;
            int so = o ^ (((o >> 8) & 7) << 4);
            *(u16x8*)((char*)smem + so) = v;
        }
    }
    __syncthreads();

    int wave = threadIdx.x >> 6;
    int lane = threadIdx.x & 63;
    int rt = rtb * 4 + wave;
    if (rt >= (N >> 4)) return;
    int r0 = rt << 4;
    int rl = lane & 15, g = lane >> 4;
    const float* xrow = X + (long)(r0 + rl) * 128 + g * 8;

    f32x4 acc[CT];
    #pragma unroll
    for (int t = 0; t < CT; t++) acc[t] = (f32x4)(0.f);

    int sw = (rl & 7) << 4;
    #pragma unroll
    for (int ks = 0; ks < 4; ks++){
        float4 xa = *(const float4*)(xrow + ks * 32);
        float4 xb = *(const float4*)(xrow + ks * 32 + 4);
        float xv[8] = {xa.x, xa.y, xa.z, xa.w, xb.x, xb.y, xb.z, xb.w};
        bf16x8 xbf;
        #pragma unroll
        for (int j = 0; j < 8; j++){
            float x = xv[j];
            if (RELU_IN) x = fmaxf(x, 0.f);
            xbf[j] = (short)f2bf(x);
        }
        int rbase = rl * 256 + ks * 64 + g * 16;
        #pragma unroll
        for (int t = 0; t < CT; t++){
            bf16x8 wh = *(const bf16x8*)((char*)smem + ((t * 4096 + rbase) ^ sw));
            bf16x8 wl = *(const bf16x8*)((char*)smem + ((HWB + t * 4096 + rbase) ^ sw));
            acc[t] = __builtin_amdgcn_mfma_f32_16x16x32_bf16(wh, xbf, acc[t], 0, 0, 0);
            acc[t] = __builtin_amdgcn_mfma_f32_16x16x32_bf16(wl, xbf, acc[t], 0, 0, 0);
        }
    }

    float ps = 0.f, pd = 0.f;
    #pragma unroll
    for (int t = 0; t < CT; t++){
        int c = c0 + t * 16 + 4 * g;
        float4 vs4 = *(const float4*)(avs + c);
        float4 vd4 = *(const float4*)(avd + c);
        ps += acc[t][0]*vs4.x + acc[t][1]*vs4.y + acc[t][2]*vs4.z + acc[t][3]*vs4.w;
        pd += acc[t][0]*vd4.x + acc[t][1]*vd4.y + acc[t][2]*vd4.z + acc[t][3]*vd4.w;
        long base = (long)(r0 + rl) * CO + c;
        if (BF16OUT){
            u16x4 pk;
            #pragma unroll
            for (int r = 0; r < 4; r++) pk[r] = f2bf(acc[t][r]);
            *(u16x4*)((unsigned short*)Hout + base) = pk;
        } else {
            float4 pv;
            pv.x = acc[t][0]; pv.y = acc[t][1]; pv.z = acc[t][2]; pv.w = acc[t][3];
            *(float4*)((float*)Hout + base) = pv;
        }
    }
    ps += __shfl_xor(ps, 16, 64); ps += __shfl_xor(ps, 32, 64);
    pd += __shfl_xor(pd, 16, 64); pd += __shfl_xor(pd, 32, 64);
    if (g == 0){
        unsafeAtomicAdd(as_out + r0 + rl, ps);
        unsafeAtomicAdd(ad_out + r0 + rl, pd);
    }
}

__device__ __forceinline__ void link_dev(
    int bid, const int* __restrict__ src, const int* __restrict__ dst,
    int E, int Etot, int* __restrict__ head, int2* __restrict__ pair)
{
    int e = bid * BLK + threadIdx.x;
    if (e >= Etot) return;
    int s, d;
    if (e < E){ s = src[e]; d = dst[e]; } else { s = e - E; d = s; }
    int old = atomicExch(head + (long)d * HS, e);
    pair[e] = make_int2(old, s);
}

// degree via chain walk + in-block EXCLUSIVE scan stored to scan1b
__device__ __forceinline__ void degscan_dev(int lb, const GP* __restrict__ g, int N, int* sh){
    int i = lb * 256 + (int)threadIdx.x;
    int len = 0;
    if (i < N){
        int c = g->head[(long)i * HS];
        while (c >= 0){ len++; c = g->pair[c].x; }
    }
    sh[threadIdx.x] = len;
    __syncthreads();
    #pragma unroll
    for (int off = 1; off < 256; off <<= 1){
        int t = (threadIdx.x >= off) ? sh[threadIdx.x - off] : 0;
        __syncthreads();
        sh[threadIdx.x] += t;
        __syncthreads();
    }
    if (i < N) g->scan1b[i] = sh[threadIdx.x] - len;   // exclusive
    if (threadIdx.x == 255) g->bsum[lb] = sh[255];
}

// fused softmax + aggregation, one wave per dst node (quarter-wave gather)
template<int CO, bool BF16H>
__device__ __forceinline__ void agg_dev(
    int bid, const int* __restrict__ rowptr, const int* __restrict__ csr_src,
    const float* __restrict__ as, const float* __restrict__ ad,
    const void* __restrict__ h, const float* __restrict__ bias,
    float* __restrict__ out, int N)
{
    constexpr int ELEMS = CO / 16;
    using uvec = typename uvec_t<ELEMS>::T;
    int node = bid * (BLK / 64) + (threadIdx.x >> 6);
    int lane = threadIdx.x & 63;
    if (node >= N) return;
    int start = rowptr[node];
    int deg   = rowptr[node + 1] - start;
    float adv = ad[node];
    int g  = lane >> 4;
    int ql = lane & 15;

    const unsigned short* hb = (const unsigned short*)h;
    const float*          hf = (const float*)h;

    if (deg <= 64){
        int   s = 0;
        float e = -1e30f;
        if (lane < deg){
            s = csr_src[start + lane];
            float v = as[s] + adv;
            e = v > 0.f ? v : NEG_SLOPE * v;
        }
        float m = e;
        #pragma unroll
        for (int off = 32; off; off >>= 1) m = fmaxf(m, __shfl_xor(m, off, 64));
        float ex = (lane < deg) ? __expf(e - m) : 0.f;
        float sum = ex;
        #pragma unroll
        for (int off = 32; off; off >>= 1) sum += __shfl_xor(sum, off, 64);
        float alpha = ex / (sum + 1e-16f);

        float acc[ELEMS];
        #pragma unroll
        for (int i = 0; i < ELEMS; i++) acc[i] = 0.f;

        int j = 0;
        for (; j + 7 < deg; j += 8){
            int e0 = j + g, e1 = j + 4 + g;
            int   s0 = __shfl(s, e0, 64),      s1 = __shfl(s, e1, 64);
            float a0 = __shfl(alpha, e0, 64),  a1 = __shfl(alpha, e1, 64);
            if (BF16H){
                uvec h0 = *(const uvec*)(hb + (long)s0 * CO + ql * ELEMS);
                uvec h1 = *(const uvec*)(hb + (long)s1 * CO + ql * ELEMS);
                #pragma unroll
                for (int i = 0; i < ELEMS; i++)
                    acc[i] += a0 * bf2f(h0[i]) + a1 * bf2f(h1[i]);
            } else {
                float4 h0 = *(const float4*)(hf + (long)s0 * CO + ql * ELEMS);
                float4 h1 = *(const float4*)(hf + (long)s1 * CO + ql * ELEMS);
                acc[0]       += a0 * h0.x + a1 * h1.x;
                acc[1]       += a0 * h0.y + a1 * h1.y;
                acc[2]       += a0 * h0.z + a1 * h1.z;
                acc[ELEMS-1] += a0 * h0.w + a1 * h1.w;
            }
        }
        for (; j + 3 < deg; j += 4){
            int e0 = j + g;
            int   s0 = __shfl(s, e0, 64);
            float a0 = __shfl(alpha, e0, 64);
            if (BF16H){
                uvec h0 = *(const uvec*)(hb + (long)s0 * CO + ql * ELEMS);
                #pragma unroll
                for (int i = 0; i < ELEMS; i++) acc[i] += a0 * bf2f(h0[i]);
            } else {
                float4 h0 = *(const float4*)(hf + (long)s0 * CO + ql * ELEMS);
                acc[0] += a0 * h0.x; acc[1] += a0 * h0.y;
                acc[2] += a0 * h0.z; acc[ELEMS-1] += a0 * h0.w;
            }
        }
        if (j < deg){
            int rem = deg - j;
            int e0 = min(j + g, deg - 1);
            int   s0 = __shfl(s, e0, 64);
            float a0 = __shfl(alpha, e0, 64);
            if (g < rem){
                if (BF16H){
                    uvec h0 = *(const uvec*)(hb + (long)s0 * CO + ql * ELEMS);
                    #pragma unroll
                    for (int i = 0; i < ELEMS; i++) acc[i] += a0 * bf2f(h0[i]);
                } else {
                    float4 h0 = *(const float4*)(hf + (long)s0 * CO + ql * ELEMS);
                    acc[0] += a0 * h0.x; acc[1] += a0 * h0.y;
                    acc[2] += a0 * h0.z; acc[ELEMS-1] += a0 * h0.w;
                }
            }
        }
        #pragma unroll
        for (int i = 0; i < ELEMS; i++){
            acc[i] += __shfl_xor(acc[i], 16, 64);
            acc[i] += __shfl_xor(acc[i], 32, 64);
        }
        if (g == 0){
            float* o = out + (long)node * CO + ql * ELEMS;
            #pragma unroll
            for (int i = 0; i < ELEMS; i += 4){
                float4 ov;
                ov.x = acc[i+0] + bias[ql * ELEMS + i + 0];
                ov.y = acc[i+1] + bias[ql * ELEMS + i + 1];
                ov.z = acc[i+2] + bias[ql * ELEMS + i + 2];
                ov.w = acc[i+3] + bias[ql * ELEMS + i + 3];
                *(float4*)(o + i) = ov;
            }
        }
    } else {
        constexpr int VPL = CO / 64;
        float accf[VPL];
        #pragma unroll
        for (int i = 0; i < VPL; i++) accf[i] = 0.f;
        float m = -1e30f;
        for (int jj = lane; jj < deg; jj += 64){
            int sj = csr_src[start + jj];
            float v = as[sj] + adv; v = v > 0.f ? v : NEG_SLOPE * v;
            m = fmaxf(m, v);
        }
        #pragma unroll
        for (int off = 32; off; off >>= 1) m = fmaxf(m, __shfl_xor(m, off, 64));
        float sum = 0.f;
        for (int jj = lane; jj < deg; jj += 64){
            int sj = csr_src[start + jj];
            float v = as[sj] + adv; v = v > 0.f ? v : NEG_SLOPE * v;
            sum += __expf(v - m);
        }
        #pragma unroll
        for (int off = 32; off; off >>= 1) sum += __shfl_xor(sum, off, 64);
        float inv = 1.f / (sum + 1e-16f);
        for (int jj = 0; jj < deg; jj++){
            int sj = csr_src[start + jj];
            float v = as[sj] + adv; v = v > 0.f ? v : NEG_SLOPE * v;
            float aj = __expf(v - m) * inv;
            if (BF16H){
                const unsigned short* hr = hb + (long)sj * CO + lane * VPL;
                #pragma unroll
                for (int i = 0; i < VPL; i++) accf[i] += aj * bf2f(hr[i]);
            } else {
                const float* hr = hf + (long)sj * CO + lane * VPL;
                #pragma unroll
                for (int i = 0; i < VPL; i++) accf[i] += aj * hr[i];
            }
        }
        float* o = out + (long)node * CO + lane * VPL;
        #pragma unroll
        for (int i = 0; i < VPL; i++) o[i] = accf[i] + bias[lane * VPL + i];
    }
}

// ---------------- kernels ----------------
// K1: link (both graphs) + as/ad init + W prep. head pre-init'd by memset.
__global__ __launch_bounds__(BLK) void k1_link(
    GP a, GP b, int LB_a, int LB_b, int IB, int ng, int E, int Etot, int N,
    const float* __restrict__ W1, const float* __restrict__ W2,
    unsigned short* __restrict__ w1h, unsigned short* __restrict__ w1l,
    unsigned short* __restrict__ w2h, unsigned short* __restrict__ w2l)
{
    int bid = blockIdx.x;
    if (bid < LB_a){ link_dev(bid, a.src, a.dst, E, Etot, a.head, a.pair); return; }
    bid -= LB_a;
    if (bid < LB_b){ link_dev(bid, b.src, b.dst, E, Etot, b.head, b.pair); return; }
    bid -= LB_b;
    if (bid >= IB) return;
    int i = bid * BLK + threadIdx.x;
    if (i < N){
        a.as1[i] = 0.f; a.ad1[i] = 0.f; a.as2[i] = 0.f; a.ad2[i] = 0.f;
        if (ng > 1){ b.as1[i] = 0.f; b.ad1[i] = 0.f; b.as2[i] = 0.f; b.ad2[i] = 0.f; }
    }
    if (i < 128 * 128){
        int c = i >> 7, k = i & 127;
        float w = W1[k * 128 + c];
        unsigned short hi = f2bf(w);
        w1h[i] = hi; w1l[i] = f2bf(w - bf2f(hi));
        if (i < 64 * 128){
            float w2 = W2[k * 64 + c];
            unsigned short hi2 = f2bf(w2);
            w2h[i] = hi2; w2l[i] = f2bf(w2 - bf2f(hi2));
        }
    }
}

// K2: degscan (chain walks, latency) overlapped with layer-1 GEMM (MFMA/LDS)
__global__ __launch_bounds__(256, 4) void k2_gemm1(
    GP a, GP b, const unsigned short* __restrict__ w1h, const unsigned short* __restrict__ w1l,
    const float* __restrict__ avs1, const float* __restrict__ avd1,
    int DS_a, int DS_b, int GB_a, int GB_b, int N)
{
    __shared__ unsigned short smem[16384];   // 32KB; degscan reuses first 1KB as int[256]
    int bid = blockIdx.x;
    if (bid < DS_a){ degscan_dev(bid, &a, N, (int*)smem); return; }
    bid -= DS_a;
    if (bid < DS_b){ degscan_dev(bid, &b, N, (int*)smem); return; }
    bid -= DS_b;
    if (bid < GB_a) gemm_dev<128,4,false,true>(bid, a.X, w1h, w1l, avs1, avd1, a.h1b, a.as1, a.ad1, N, smem);
    else { bid -= GB_a; if (bid < GB_b) gemm_dev<128,4,false,true>(bid, b.X, w1h, w1l, avs1, avd1, b.h1b, b.as1, b.ad1, N, smem); }
}

// K3: rowptr + unzip; per-block inline scan of bsum (nb <= 256)
__global__ __launch_bounds__(256) void k3_ptrunzip(GP a, GP b, int nb_a, int nb_b, int N, int Etot){
    int bid = blockIdx.x; const GP* g; int lb; int nb;
    if (bid < nb_a){ g = &a; lb = bid; nb = nb_a; }
    else { lb = bid - nb_a; if (lb >= nb_b) return; g = &b; nb = nb_b; }
    __shared__ int sh[256];
    int v = ((int)threadIdx.x < nb) ? g->bsum[threadIdx.x] : 0;
    sh[threadIdx.x] = v;
    __syncthreads();
    #pragma unroll
    for (int off = 1; off < 256; off <<= 1){
        int t = (threadIdx.x >= off) ? sh[threadIdx.x - off] : 0;
        __syncthreads();
        sh[threadIdx.x] += t;
        __syncthreads();
    }
    int base = (lb > 0) ? sh[lb - 1] : 0;
    int i = lb * 256 + (int)threadIdx.x;
    if (i >= N) return;
    int pos = g->scan1b[i] + base;
    g->rowptr[i] = pos;
    if (i == 0) g->rowptr[N] = Etot;
    int c = g->head[(long)i * HS];
    while (c >= 0){
        int2 p = g->pair[c];
        g->csrsrc[pos++] = p.y;
        c = p.x;
    }
}

__global__ __launch_bounds__(256, 4) void gemm2_k(
    GP a, GP b, const unsigned short* __restrict__ w2h, const unsigned short* __restrict__ w2l,
    const float* __restrict__ avs2, const float* __restrict__ avd2, int GB_a, int GB_b, int N)
{
    __shared__ unsigned short smem[8192];    // 16KB: W2 chunk hi+lo
    int bid = blockIdx.x;
    if (bid < GB_a) gemm_dev<64,2,true,true>(bid, a.agg1, w2h, w2l, avs2, avd2, a.h2b, a.as2, a.ad2, N, smem);
    else { bid -= GB_a; if (bid < GB_b) gemm_dev<64,2,true,true>(bid, b.agg1, w2h, w2l, avs2, avd2, b.h2b, b.as2, b.ad2, N, smem); }
}

template<int CO, bool BF16H>
__global__ __launch_bounds__(BLK) void agg2_k(GP a, GP b, const float* bias, int AB_a, int AB_b, int N){
    int bid = blockIdx.x; const GP* g; int lb;
    if (bid < AB_a){ g = &a; lb = bid; }
    else { lb = bid - AB_a; if (lb >= AB_b) return; g = &b; }
    const float* as; const float* ad; const void* h; float* outp;
    if constexpr (CO == 128){ as = g->as1; ad = g->ad1; h = g->h1b; outp = g->agg1; }
    else                    { as = g->as2; ad = g->ad2; h = g->h2b; outp = g->outp; }
    agg_dev<CO, BF16H>(lb, g->rowptr, g->csrsrc, as, ad, h, bias, outp, N);
}

// ---------------- host ----------------
extern "C" void kernel_launch(void* const* d_in, const int* in_sizes, int n_in,
                              void* d_out, int out_size, void* d_ws, size_t ws_size,
                              hipStream_t stream)
{
    const float* fea  = (const float*)d_in[0];
    const int*   ei   = (const int*)  d_in[1];
    const float* W1   = (const float*)d_in[2];
    const float* av_s1= (const float*)d_in[3];
    const float* av_d1= (const float*)d_in[4];
    const float* b1   = (const float*)d_in[5];
    const float* W2   = (const float*)d_in[6];
    const float* av_s2= (const float*)d_in[7];
    const float* av_d2= (const float*)d_in[8];
    const float* b2   = (const float*)d_in[9];
    float* out = (float*)d_out;

    const int B = 2;
    const int N = out_size / (B * 64);          // 50000
    const int E = in_sizes[1] / (2 * B);        // 800000
    const int Etot = E + N;

    // per-graph float budget: h1b N*64 + agg1 N*128 + h2b N*32 + as/ad 4N + head 16N
    // + scan1b N + bsum 256 + rowptr N+2 + csrsrc Etot + pair 2*Etot
    size_t pg = (size_t)N * (64 + 128 + 32 + 4 + HS + 1) + 256 + (size_t)(N + 2)
              + 3 * (size_t)Etot + 16;
    size_t wtf = 8192 + 8192 + 4096 + 4096;
    bool fused = (ws_size >= (2 * pg + wtf + 64) * sizeof(float));
    int NG = fused ? 2 : 1;

    float* ws = (float*)d_ws;
    size_t off = 0;
    unsigned short* w1h = (unsigned short*)(ws + off); off += 8192;
    unsigned short* w1l = (unsigned short*)(ws + off); off += 8192;
    unsigned short* w2h = (unsigned short*)(ws + off); off += 4096;
    unsigned short* w2l = (unsigned short*)(ws + off); off += 4096;

    int* headbase = (int*)(ws + off); off += (size_t)NG * N * HS;

    GP g[2];
    for (int gi = 0; gi < NG; gi++){
        GP p;
        p.head  = headbase + (size_t)gi * N * HS;
        p.h1b   = (unsigned short*)(ws + off); off += (size_t)N * 64;
        p.agg1  = ws + off; off += (size_t)N * 128;
        p.h2b   = (unsigned short*)(ws + off); off += (size_t)N * 32;
        p.as1   = ws + off; off += N;
        p.ad1   = ws + off; off += N;
        p.as2   = ws + off; off += N;
        p.ad2   = ws + off; off += N;
        p.scan1b= (int*)(ws + off); off += N;
        p.bsum  = (int*)(ws + off); off += 256;
        p.rowptr= (int*)(ws + off); off += (size_t)(N + 2);
        p.csrsrc= (int*)(ws + off); off += Etot;
        off += (off & 1);
        p.pair  = (int2*)(ws + off); off += 2 * (size_t)Etot;
        g[gi] = p;
    }

    const int RT  = N >> 4;
    const int GB1 = cdiv(RT, 4) * 2;
    const int GB2 = cdiv(RT, 4) * 2;
    const int LB  = cdiv(Etot, BLK);
    const int nb  = cdiv(N, 256);          // 196 (<=256 required by k3)
    const int IB  = cdiv(N, BLK);
    const int AB  = cdiv(N, BLK / 64);

    if (fused){
        for (int bi = 0; bi < 2; bi++){
            g[bi].src = ei + (size_t)bi * 2 * E;
            g[bi].dst = g[bi].src + E;
            g[bi].X   = fea + (size_t)bi * N * 128;
            g[bi].outp= out + (size_t)bi * N * 64;
        }
        hipMemsetAsync(headbase, 0xFF, (size_t)2 * N * HS * sizeof(int), stream);
        k1_link<<<2*LB + IB, BLK, 0, stream>>>(g[0], g[1], LB, LB, IB, 2, E, Etot, N,
                                               W1, W2, w1h, w1l, w2h, w2l);
        k2_gemm1<<<2*nb + 2*GB1, 256, 0, stream>>>(g[0], g[1], w1h, w1l, av_s1, av_d1,
                                                   nb, nb, GB1, GB1, N);
        k3_ptrunzip<<<2*nb, 256, 0, stream>>>(g[0], g[1], nb, nb, N, Etot);
        agg2_k<128,true> <<<2*AB, BLK, 0, stream>>>(g[0], g[1], b1, AB, AB, N);
        gemm2_k <<<2*GB2, 256, 0, stream>>>(g[0], g[1], w2h, w2l, av_s2, av_d2, GB2, GB2, N);
        agg2_k<64,true> <<<2*AB, BLK, 0, stream>>>(g[0], g[1], b2, AB, AB, N);
    } else {
        for (int bi = 0; bi < B; bi++){
            GP p = g[0];
            p.src = ei + (size_t)bi * 2 * E;
            p.dst = p.src + E;
            p.X   = fea + (size_t)bi * N * 128;
            p.outp= out + (size_t)bi * N * 64;
            hipMemsetAsync(headbase, 0xFF, (size_t)N * HS * sizeof(int), stream);
            k1_link<<<LB + IB, BLK, 0, stream>>>(p, p, LB, 0, IB, 1, E, Etot, N,
                                                 W1, W2, w1h, w1l, w2h, w2l);
            k2_gemm1<<<nb + GB1, 256, 0, stream>>>(p, p, w1h, w1l, av_s1, av_d1,
                                                   nb, 0, GB1, 0, N);
            k3_ptrunzip<<<nb, 256, 0, stream>>>(p, p, nb, 0, N, Etot);
            agg2_k<128,true> <<<AB, BLK, 0, stream>>>(p, p, b1, AB, 0, N);
            gemm2_k <<<GB2, 256, 0, stream>>>(p, p, w2h, w2l, av_s2, av_d2, GB2, 0, N);
            agg2_k<64,true> <<<AB, BLK, 0, stream>>>(p, p, b2, AB, 0, N);
        }
    }
}

// Round 12
// 230.737 us; speedup vs baseline: 1.3386x; 1.3386x over previous
//
#include <hip/hip_runtime.h>

#define NEG_SLOPE 0.2f
static constexpr int BLK = 256;
static constexpr int EPB = 4096;   // edges per bucket-pass block
static constexpr int CAP = 6144;   // per-bucket capacity (mean 4336, +27 sigma)

typedef short bf16x8 __attribute__((ext_vector_type(8)));
typedef float f32x4  __attribute__((ext_vector_type(4)));
typedef unsigned short u16x8 __attribute__((ext_vector_type(8)));
typedef unsigned short u16x4 __attribute__((ext_vector_type(4)));

template<int NE> struct uvec_t;
template<> struct uvec_t<4>{ using T = u16x4; };
template<> struct uvec_t<8>{ using T = u16x8; };

static inline int cdiv(long a, long b){ return (int)((a + b - 1) / b); }

__device__ __forceinline__ unsigned short f2bf(float f){
    unsigned u = __float_as_uint(f);
    u += 0x7fff + ((u >> 16) & 1);          // RNE
    return (unsigned short)(u >> 16);
}
__device__ __forceinline__ float bf2f(unsigned short h){
    return __uint_as_float(((unsigned)h) << 16);
}

// ---------------- per-graph pointer bundle ----------------
struct GP {
    const int* src; const int* dst; const float* X;
    int* gcnt; int* gbase; int* ebuf; int* rowptr; int* csrsrc;
    unsigned short* h1b; float* agg1; unsigned short* h2b;
    float *as1, *ad1, *as2, *ad2; float* outp;
};

// ---------------- LDS-staged MFMA GEMM: h = W_split x bf16(x) ----------------
template<int CO, int CT, bool RELU_IN, bool BF16OUT>
__device__ __forceinline__ void gemm_dev(
    int bid, const float* __restrict__ X,
    const unsigned short* __restrict__ Wt_hi, const unsigned short* __restrict__ Wt_lo,
    const float* __restrict__ avs, const float* __restrict__ avd,
    void* __restrict__ Hout, float* __restrict__ as_out, float* __restrict__ ad_out,
    int N, unsigned short* smem)
{
    constexpr int CHUNKS = CO / (CT * 16);
    constexpr int HWB = CT * 4096;
    int ch, rtb;
    if (CHUNKS == 1){ ch = 0; rtb = bid; } else { ch = bid & 1; rtb = bid >> 1; }
    int c0 = ch * (CT * 16);

    {
        const char* srch = (const char*)(Wt_hi + (size_t)c0 * 128);
        const char* srcl = (const char*)(Wt_lo + (size_t)c0 * 128);
        #pragma unroll
        for (int it = 0; it < CT * 2; ++it){
            int o = (it * 256 + (int)threadIdx.x) * 16;
            const char* sp = (o < HWB) ? (srch + o) : (srcl + (o - HWB));
            u16x8 v = *(const u16x8*)sp;
            int so = o ^ (((o >> 8) & 7) << 4);
            *(u16x8*)((char*)smem + so) = v;
        }
    }
    __syncthreads();

    int wave = threadIdx.x >> 6;
    int lane = threadIdx.x & 63;
    int rt = rtb * 4 + wave;
    if (rt >= (N >> 4)) return;
    int r0 = rt << 4;
    int rl = lane & 15, g = lane >> 4;
    const float* xrow = X + (long)(r0 + rl) * 128 + g * 8;

    f32x4 acc[CT];
    #pragma unroll
    for (int t = 0; t < CT; t++) acc[t] = (f32x4)(0.f);

    int sw = (rl & 7) << 4;
    #pragma unroll
    for (int ks = 0; ks < 4; ks++){
        float4 xa = *(const float4*)(xrow + ks * 32);
        float4 xb = *(const float4*)(xrow + ks * 32 + 4);
        float xv[8] = {xa.x, xa.y, xa.z, xa.w, xb.x, xb.y, xb.z, xb.w};
        bf16x8 xbf;
        #pragma unroll
        for (int j = 0; j < 8; j++){
            float x = xv[j];
            if (RELU_IN) x = fmaxf(x, 0.f);
            xbf[j] = (short)f2bf(x);
        }
        int rbase = rl * 256 + ks * 64 + g * 16;
        #pragma unroll
        for (int t = 0; t < CT; t++){
            bf16x8 wh = *(const bf16x8*)((char*)smem + ((t * 4096 + rbase) ^ sw));
            bf16x8 wl = *(const bf16x8*)((char*)smem + ((HWB + t * 4096 + rbase) ^ sw));
            acc[t] = __builtin_amdgcn_mfma_f32_16x16x32_bf16(wh, xbf, acc[t], 0, 0, 0);
            acc[t] = __builtin_amdgcn_mfma_f32_16x16x32_bf16(wl, xbf, acc[t], 0, 0, 0);
        }
    }

    float ps = 0.f, pd = 0.f;
    #pragma unroll
    for (int t = 0; t < CT; t++){
        int c = c0 + t * 16 + 4 * g;
        float4 vs4 = *(const float4*)(avs + c);
        float4 vd4 = *(const float4*)(avd + c);
        ps += acc[t][0]*vs4.x + acc[t][1]*vs4.y + acc[t][2]*vs4.z + acc[t][3]*vs4.w;
        pd += acc[t][0]*vd4.x + acc[t][1]*vd4.y + acc[t][2]*vd4.z + acc[t][3]*vd4.w;
        long base = (long)(r0 + rl) * CO + c;
        if (BF16OUT){
            u16x4 pk;
            #pragma unroll
            for (int r = 0; r < 4; r++) pk[r] = f2bf(acc[t][r]);
            *(u16x4*)((unsigned short*)Hout + base) = pk;
        } else {
            float4 pv;
            pv.x = acc[t][0]; pv.y = acc[t][1]; pv.z = acc[t][2]; pv.w = acc[t][3];
            *(float4*)((float*)Hout + base) = pv;
        }
    }
    ps += __shfl_xor(ps, 16, 64); ps += __shfl_xor(ps, 32, 64);
    pd += __shfl_xor(pd, 16, 64); pd += __shfl_xor(pd, 32, 64);
    if (g == 0){
        unsafeAtomicAdd(as_out + r0 + rl, ps);
        unsafeAtomicAdd(ad_out + r0 + rl, pd);
    }
}

// ---------------- coarse bucket pass (LDS histogram + reserved scatter) ----------------
// Packs edge as (src<<16)|dst (requires N <= 65536). Only 196 global atomics per block.
__device__ __forceinline__ void bucket_dev(
    int bid, const GP* __restrict__ g, int E, int Etot, int nbk, unsigned short* smem)
{
    int* spk   = (int*)smem;          // 4096 ints
    int* shist = spk + 4096;          // 256
    int* sbase = shist + 256;         // 256
    int tid = (int)threadIdx.x;
    for (int i = tid; i < nbk; i += 256) shist[i] = 0;
    __syncthreads();
    int e0 = bid * EPB;
    #pragma unroll
    for (int i = 0; i < EPB / 256; i++){
        int idx = i * 256 + tid; int e = e0 + idx;
        unsigned p = 0xFFFFFFFFu;
        if (e < Etot){
            int s, d;
            if (e < E){ s = g->src[e]; d = g->dst[e]; } else { s = e - E; d = s; }
            p = ((unsigned)s << 16) | (unsigned)d;
            atomicAdd(&shist[d >> 8], 1);
        }
        spk[idx] = (int)p;
    }
    __syncthreads();
    for (int i = tid; i < nbk; i += 256){
        sbase[i] = atomicAdd(&g->gcnt[i], shist[i]);
        shist[i] = 0;                 // reuse as fill counter
    }
    __syncthreads();
    #pragma unroll
    for (int i = 0; i < EPB / 256; i++){
        int idx = i * 256 + tid;
        unsigned p = (unsigned)spk[idx];
        if (p != 0xFFFFFFFFu){
            int d = (int)(p & 0xFFFFu); int b = d >> 8;
            int r = sbase[b] + atomicAdd(&shist[b], 1);
            if (r < CAP) g->ebuf[(size_t)b * CAP + r] = (int)p;
        }
    }
}

// ---------------- fine pass: per-bucket CSR (rowptr + sorted csrsrc) ----------------
__device__ __forceinline__ void fine_dev(int k, const GP* __restrict__ g, int N, int Etot)
{
    __shared__ int pk2[CAP];
    __shared__ int fs[256];
    __shared__ int fill[256];
    __shared__ int fh[256];
    int tid = (int)threadIdx.x;
    int cnt = min(g->gcnt[k], CAP);
    int bb  = g->gbase[k];
    for (int i = tid; i < cnt; i += 256) pk2[i] = g->ebuf[(size_t)k * CAP + i];
    fh[tid] = 0; fill[tid] = 0;
    __syncthreads();
    for (int i = tid; i < cnt; i += 256) atomicAdd(&fh[pk2[i] & 255], 1);
    __syncthreads();
    int v = fh[tid];
    fs[tid] = v;
    __syncthreads();
    #pragma unroll
    for (int off = 1; off < 256; off <<= 1){
        int t = (tid >= off) ? fs[tid - off] : 0;
        __syncthreads();
        fs[tid] += t;
        __syncthreads();
    }
    int excl = fs[tid] - v;
    __syncthreads();
    fs[tid] = excl;
    __syncthreads();
    int node = k * 256 + tid;
    if (node < N) g->rowptr[node] = bb + excl;
    if (k == 0 && tid == 0) g->rowptr[N] = Etot;
    for (int i = tid; i < cnt; i += 256){
        unsigned p = (unsigned)pk2[i];
        int f = (int)(p & 255u);
        int r = atomicAdd(&fill[f], 1);
        g->csrsrc[bb + fs[f] + r] = (int)(p >> 16);
    }
}

// ---------------- fused softmax + aggregation (quarter-wave gather) ----------------
template<int CO, bool BF16H>
__device__ __forceinline__ void agg_dev(
    int bid, const int* __restrict__ rowptr, const int* __restrict__ csr_src,
    const float* __restrict__ as, const float* __restrict__ ad,
    const void* __restrict__ h, const float* __restrict__ bias,
    float* __restrict__ out, int N)
{
    constexpr int ELEMS = CO / 16;
    using uvec = typename uvec_t<ELEMS>::T;
    int node = bid * (BLK / 64) + (threadIdx.x >> 6);
    int lane = threadIdx.x & 63;
    if (node >= N) return;
    int start = rowptr[node];
    int deg   = rowptr[node + 1] - start;
    float adv = ad[node];
    int g  = lane >> 4;
    int ql = lane & 15;

    const unsigned short* hb = (const unsigned short*)h;
    const float*          hf = (const float*)h;

    if (deg <= 64){
        int   s = 0;
        float e = -1e30f;
        if (lane < deg){
            s = csr_src[start + lane];
            float v = as[s] + adv;
            e = v > 0.f ? v : NEG_SLOPE * v;
        }
        float m = e;
        #pragma unroll
        for (int off = 32; off; off >>= 1) m = fmaxf(m, __shfl_xor(m, off, 64));
        float ex = (lane < deg) ? __expf(e - m) : 0.f;
        float sum = ex;
        #pragma unroll
        for (int off = 32; off; off >>= 1) sum += __shfl_xor(sum, off, 64);
        float alpha = ex / (sum + 1e-16f);

        float acc[ELEMS];
        #pragma unroll
        for (int i = 0; i < ELEMS; i++) acc[i] = 0.f;

        int j = 0;
        for (; j + 7 < deg; j += 8){
            int e0 = j + g, e1 = j + 4 + g;
            int   s0 = __shfl(s, e0, 64),      s1 = __shfl(s, e1, 64);
            float a0 = __shfl(alpha, e0, 64),  a1 = __shfl(alpha, e1, 64);
            if (BF16H){
                uvec h0 = *(const uvec*)(hb + (long)s0 * CO + ql * ELEMS);
                uvec h1 = *(const uvec*)(hb + (long)s1 * CO + ql * ELEMS);
                #pragma unroll
                for (int i = 0; i < ELEMS; i++)
                    acc[i] += a0 * bf2f(h0[i]) + a1 * bf2f(h1[i]);
            } else {
                float4 h0 = *(const float4*)(hf + (long)s0 * CO + ql * ELEMS);
                float4 h1 = *(const float4*)(hf + (long)s1 * CO + ql * ELEMS);
                acc[0]       += a0 * h0.x + a1 * h1.x;
                acc[1]       += a0 * h0.y + a1 * h1.y;
                acc[2]       += a0 * h0.z + a1 * h1.z;
                acc[ELEMS-1] += a0 * h0.w + a1 * h1.w;
            }
        }
        for (; j + 3 < deg; j += 4){
            int e0 = j + g;
            int   s0 = __shfl(s, e0, 64);
            float a0 = __shfl(alpha, e0, 64);
            if (BF16H){
                uvec h0 = *(const uvec*)(hb + (long)s0 * CO + ql * ELEMS);
                #pragma unroll
                for (int i = 0; i < ELEMS; i++) acc[i] += a0 * bf2f(h0[i]);
            } else {
                float4 h0 = *(const float4*)(hf + (long)s0 * CO + ql * ELEMS);
                acc[0] += a0 * h0.x; acc[1] += a0 * h0.y;
                acc[2] += a0 * h0.z; acc[ELEMS-1] += a0 * h0.w;
            }
        }
        if (j < deg){
            int rem = deg - j;
            int e0 = min(j + g, deg - 1);
            int   s0 = __shfl(s, e0, 64);
            float a0 = __shfl(alpha, e0, 64);
            if (g < rem){
                if (BF16H){
                    uvec h0 = *(const uvec*)(hb + (long)s0 * CO + ql * ELEMS);
                    #pragma unroll
                    for (int i = 0; i < ELEMS; i++) acc[i] += a0 * bf2f(h0[i]);
                } else {
                    float4 h0 = *(const float4*)(hf + (long)s0 * CO + ql * ELEMS);
                    acc[0] += a0 * h0.x; acc[1] += a0 * h0.y;
                    acc[2] += a0 * h0.z; acc[ELEMS-1] += a0 * h0.w;
                }
            }
        }
        #pragma unroll
        for (int i = 0; i < ELEMS; i++){
            acc[i] += __shfl_xor(acc[i], 16, 64);
            acc[i] += __shfl_xor(acc[i], 32, 64);
        }
        if (g == 0){
            float* o = out + (long)node * CO + ql * ELEMS;
            #pragma unroll
            for (int i = 0; i < ELEMS; i += 4){
                float4 ov;
                ov.x = acc[i+0] + bias[ql * ELEMS + i + 0];
                ov.y = acc[i+1] + bias[ql * ELEMS + i + 1];
                ov.z = acc[i+2] + bias[ql * ELEMS + i + 2];
                ov.w = acc[i+3] + bias[ql * ELEMS + i + 3];
                *(float4*)(o + i) = ov;
            }
        }
    } else {
        constexpr int VPL = CO / 64;
        float accf[VPL];
        #pragma unroll
        for (int i = 0; i < VPL; i++) accf[i] = 0.f;
        float m = -1e30f;
        for (int jj = lane; jj < deg; jj += 64){
            int sj = csr_src[start + jj];
            float v = as[sj] + adv; v = v > 0.f ? v : NEG_SLOPE * v;
            m = fmaxf(m, v);
        }
        #pragma unroll
        for (int off = 32; off; off >>= 1) m = fmaxf(m, __shfl_xor(m, off, 64));
        float sum = 0.f;
        for (int jj = lane; jj < deg; jj += 64){
            int sj = csr_src[start + jj];
            float v = as[sj] + adv; v = v > 0.f ? v : NEG_SLOPE * v;
            sum += __expf(v - m);
        }
        #pragma unroll
        for (int off = 32; off; off >>= 1) sum += __shfl_xor(sum, off, 64);
        float inv = 1.f / (sum + 1e-16f);
        for (int jj = 0; jj < deg; jj++){
            int sj = csr_src[start + jj];
            float v = as[sj] + adv; v = v > 0.f ? v : NEG_SLOPE * v;
            float aj = __expf(v - m) * inv;
            if (BF16H){
                const unsigned short* hr = hb + (long)sj * CO + lane * VPL;
                #pragma unroll
                for (int i = 0; i < VPL; i++) accf[i] += aj * bf2f(hr[i]);
            } else {
                const float* hr = hf + (long)sj * CO + lane * VPL;
                #pragma unroll
                for (int i = 0; i < VPL; i++) accf[i] += aj * hr[i];
            }
        }
        float* o = out + (long)node * CO + lane * VPL;
        #pragma unroll
        for (int i = 0; i < VPL; i++) o[i] = accf[i] + bias[lane * VPL + i];
    }
}

// ---------------- kernels ----------------
__global__ __launch_bounds__(BLK) void prep_k(
    const float* __restrict__ W1, const float* __restrict__ W2,
    unsigned short* __restrict__ w1h, unsigned short* __restrict__ w1l,
    unsigned short* __restrict__ w2h, unsigned short* __restrict__ w2l)
{
    int i = blockIdx.x * BLK + threadIdx.x;
    if (i < 128 * 128){
        int c = i >> 7, k = i & 127;
        float w = W1[k * 128 + c];
        unsigned short hi = f2bf(w);
        w1h[i] = hi; w1l[i] = f2bf(w - bf2f(hi));
        if (i < 64 * 128){
            float w2 = W2[k * 64 + c];
            unsigned short hi2 = f2bf(w2);
            w2h[i] = hi2; w2l[i] = f2bf(w2 - bf2f(hi2));
        }
    }
}

// kA: coarse bucket pass (both graphs) + layer-1 GEMM (both graphs)
__global__ __launch_bounds__(256, 4) void kA(
    GP a, GP b, const unsigned short* __restrict__ w1h, const unsigned short* __restrict__ w1l,
    const float* __restrict__ avs1, const float* __restrict__ avd1,
    int EB_a, int EB_b, int GB_a, int GB_b, int E, int Etot, int N, int nbk)
{
    __shared__ unsigned short smem[16384];   // 32KB; bucket role uses first 18KB
    int bid = blockIdx.x;
    if (bid < EB_a){ bucket_dev(bid, &a, E, Etot, nbk, smem); return; }
    bid -= EB_a;
    if (bid < EB_b){ bucket_dev(bid, &b, E, Etot, nbk, smem); return; }
    bid -= EB_b;
    if (bid < GB_a){ gemm_dev<128,4,false,true>(bid, a.X, w1h, w1l, avs1, avd1, a.h1b, a.as1, a.ad1, N, smem); return; }
    bid -= GB_a;
    if (bid < GB_b) gemm_dev<128,4,false,true>(bid, b.X, w1h, w1l, avs1, avd1, b.h1b, b.as1, b.ad1, N, smem);
}

__global__ __launch_bounds__(256) void kscan(GP a, GP b, int nbk){
    const GP* g = (blockIdx.x == 0) ? &a : &b;
    __shared__ int sh[256];
    int tid = (int)threadIdx.x;
    int v = (tid < nbk) ? g->gcnt[tid] : 0;
    sh[tid] = v;
    __syncthreads();
    #pragma unroll
    for (int off = 1; off < 256; off <<= 1){
        int t = (tid >= off) ? sh[tid - off] : 0;
        __syncthreads();
        sh[tid] += t;
        __syncthreads();
    }
    if (tid < nbk) g->gbase[tid] = sh[tid] - v;
}

__global__ __launch_bounds__(256) void kB(GP a, GP b, int nb_a, int nb_b, int N, int Etot){
    int bid = blockIdx.x; const GP* g; int k;
    if (bid < nb_a){ g = &a; k = bid; }
    else { k = bid - nb_a; if (k >= nb_b) return; g = &b; }
    fine_dev(k, g, N, Etot);
}

__global__ __launch_bounds__(256, 4) void gemm2_k(
    GP a, GP b, const unsigned short* __restrict__ w2h, const unsigned short* __restrict__ w2l,
    const float* __restrict__ avs2, const float* __restrict__ avd2, int GB_a, int GB_b, int N)
{
    __shared__ unsigned short smem[8192];    // 16KB: W2 chunk hi+lo
    int bid = blockIdx.x;
    if (bid < GB_a) gemm_dev<64,2,true,true>(bid, a.agg1, w2h, w2l, avs2, avd2, a.h2b, a.as2, a.ad2, N, smem);
    else { bid -= GB_a; if (bid < GB_b) gemm_dev<64,2,true,true>(bid, b.agg1, w2h, w2l, avs2, avd2, b.h2b, b.as2, b.ad2, N, smem); }
}

template<int CO, bool BF16H>
__global__ __launch_bounds__(BLK) void agg2_k(GP a, GP b, const float* bias, int AB_a, int AB_b, int N){
    int bid = blockIdx.x; const GP* g; int lb;
    if (bid < AB_a){ g = &a; lb = bid; }
    else { lb = bid - AB_a; if (lb >= AB_b) return; g = &b; }
    const float* as; const float* ad; const void* h; float* outp;
    if constexpr (CO == 128){ as = g->as1; ad = g->ad1; h = g->h1b; outp = g->agg1; }
    else                    { as = g->as2; ad = g->ad2; h = g->h2b; outp = g->outp; }
    agg_dev<CO, BF16H>(lb, g->rowptr, g->csrsrc, as, ad, h, bias, outp, N);
}

// ---------------- host ----------------
extern "C" void kernel_launch(void* const* d_in, const int* in_sizes, int n_in,
                              void* d_out, int out_size, void* d_ws, size_t ws_size,
                              hipStream_t stream)
{
    const float* fea  = (const float*)d_in[0];
    const int*   ei   = (const int*)  d_in[1];
    const float* W1   = (const float*)d_in[2];
    const float* av_s1= (const float*)d_in[3];
    const float* av_d1= (const float*)d_in[4];
    const float* b1   = (const float*)d_in[5];
    const float* W2   = (const float*)d_in[6];
    const float* av_s2= (const float*)d_in[7];
    const float* av_d2= (const float*)d_in[8];
    const float* b2   = (const float*)d_in[9];
    float* out = (float*)d_out;

    const int B = 2;
    const int N = out_size / (B * 64);          // 50000 (pack requires N <= 65536)
    const int E = in_sizes[1] / (2 * B);        // 800000
    const int Etot = E + N;
    const int nbk = (N + 255) >> 8;             // 196 coarse buckets (<=256)

    // float budget per graph: gbase 256 + ebuf nbk*CAP + rowptr N+2 + csrsrc Etot
    //                        + h1b N*64 + agg1 N*128 + h2b N*32
    size_t pg = 256 + (size_t)nbk * CAP + (size_t)(N + 2) + (size_t)Etot
              + (size_t)N * (64 + 128 + 32);
    size_t wtf = 8192 + 8192 + 4096 + 4096;
    auto total_f = [&](int ng){ return wtf + (size_t)ng * (4 * (size_t)N + 256) + (size_t)ng * pg + 64; };
    bool fused = (ws_size >= total_f(2) * sizeof(float));
    int NG = fused ? 2 : 1;

    float* ws = (float*)d_ws;
    size_t off = 0;
    unsigned short* w1h = (unsigned short*)(ws + off); off += 8192;
    unsigned short* w1l = (unsigned short*)(ws + off); off += 8192;
    unsigned short* w2h = (unsigned short*)(ws + off); off += 4096;
    unsigned short* w2l = (unsigned short*)(ws + off); off += 4096;

    // zero region: as/ad (both graphs) + gcnt (both graphs) — one memset
    float* zbase = ws + off;
    size_t znum = (size_t)NG * (4 * (size_t)N + 256);
    off += znum;

    GP g[2];
    for (int gi = 0; gi < NG; gi++){
        GP p;
        p.as1  = zbase + (size_t)gi * (4 * (size_t)N + 256);
        p.ad1  = p.as1 + N;
        p.as2  = p.ad1 + N;
        p.ad2  = p.as2 + N;
        p.gcnt = (int*)(p.ad2 + N);                    // 256 ints
        p.gbase  = (int*)(ws + off); off += 256;
        p.ebuf   = (int*)(ws + off); off += (size_t)nbk * CAP;
        p.rowptr = (int*)(ws + off); off += (size_t)(N + 2);
        p.csrsrc = (int*)(ws + off); off += Etot;
        p.h1b  = (unsigned short*)(ws + off); off += (size_t)N * 64;
        p.agg1 = ws + off; off += (size_t)N * 128;
        p.h2b  = (unsigned short*)(ws + off); off += (size_t)N * 32;
        g[gi] = p;
    }

    const int RT  = N >> 4;
    const int GB1 = cdiv(RT, 4) * 2;
    const int GB2 = cdiv(RT, 4) * 2;
    const int EBk = cdiv(Etot, EPB);            // 208 bucket blocks per graph
    const int AB  = cdiv(N, BLK / 64);

    if (fused){
        for (int bi = 0; bi < 2; bi++){
            g[bi].src = ei + (size_t)bi * 2 * E;
            g[bi].dst = g[bi].src + E;
            g[bi].X   = fea + (size_t)bi * N * 128;
            g[bi].outp= out + (size_t)bi * N * 64;
        }
        hipMemsetAsync(zbase, 0, znum * sizeof(float), stream);
        prep_k<<<cdiv(128*128, BLK), BLK, 0, stream>>>(W1, W2, w1h, w1l, w2h, w2l);
        kA<<<2*EBk + 2*GB1, 256, 0, stream>>>(g[0], g[1], w1h, w1l, av_s1, av_d1,
                                              EBk, EBk, GB1, GB1, E, Etot, N, nbk);
        kscan<<<2, 256, 0, stream>>>(g[0], g[1], nbk);
        kB<<<2*nbk, 256, 0, stream>>>(g[0], g[1], nbk, nbk, N, Etot);
        agg2_k<128,true> <<<2*AB, BLK, 0, stream>>>(g[0], g[1], b1, AB, AB, N);
        gemm2_k <<<2*GB2, 256, 0, stream>>>(g[0], g[1], w2h, w2l, av_s2, av_d2, GB2, GB2, N);
        agg2_k<64,true> <<<2*AB, BLK, 0, stream>>>(g[0], g[1], b2, AB, AB, N);
    } else {
        prep_k<<<cdiv(128*128, BLK), BLK, 0, stream>>>(W1, W2, w1h, w1l, w2h, w2l);
        for (int bi = 0; bi < B; bi++){
            GP p = g[0];
            p.src = ei + (size_t)bi * 2 * E;
            p.dst = p.src + E;
            p.X   = fea + (size_t)bi * N * 128;
            p.outp= out + (size_t)bi * N * 64;
            hipMemsetAsync(zbase, 0, znum * sizeof(float), stream);
            kA<<<EBk + GB1, 256, 0, stream>>>(p, p, w1h, w1l, av_s1, av_d1,
                                              EBk, 0, GB1, 0, E, Etot, N, nbk);
            kscan<<<1, 256, 0, stream>>>(p, p, nbk);
            kB<<<nbk, 256, 0, stream>>>(p, p, nbk, 0, N, Etot);
            agg2_k<128,true> <<<AB, BLK, 0, stream>>>(p, p, b1, AB, 0, N);
            gemm2_k <<<GB2, 256, 0, stream>>>(p, p, w2h, w2l, av_s2, av_d2, GB2, 0, N);
            agg2_k<64,true> <<<AB, BLK, 0, stream>>>(p, p, b2, AB, 0, N);
        }
    }
}

// Round 13
// 213.731 us; speedup vs baseline: 1.4451x; 1.0796x over previous
//
#include <hip/hip_runtime.h>

#define NEG_SLOPE 0.2f
static constexpr int BLK = 256;
static constexpr int EPB = 4096;   // edges per bucket-pass block
static constexpr int CAP = 6144;   // per-bucket capacity (mean 4336, +27 sigma)

typedef short bf16x8 __attribute__((ext_vector_type(8)));
typedef float f32x4  __attribute__((ext_vector_type(4)));
typedef unsigned short u16x8 __attribute__((ext_vector_type(8)));
typedef unsigned short u16x4 __attribute__((ext_vector_type(4)));

template<int NE> struct uvec_t;
template<> struct uvec_t<4>{ using T = u16x4; };
template<> struct uvec_t<8>{ using T = u16x8; };

static inline int cdiv(long a, long b){ return (int)((a + b - 1) / b); }

__device__ __forceinline__ unsigned short f2bf(float f){
    unsigned u = __float_as_uint(f);
    u += 0x7fff + ((u >> 16) & 1);          // RNE
    return (unsigned short)(u >> 16);
}
__device__ __forceinline__ float bf2f(unsigned short h){
    return __uint_as_float(((unsigned)h) << 16);
}
__device__ __forceinline__ float lrelu(float v){
    return v > 0.f ? v : NEG_SLOPE * v;
}

// ---------------- per-graph pointer bundle ----------------
struct GP {
    const int* src; const int* dst; const float* X;
    int* gcnt; int* gbase; int* ebuf; int* rowptr; int* csrsrc;
    unsigned short* h1b; float* agg1; unsigned short* h2b;
    float *as1, *ad1, *as2, *ad2; float* outp;
};

// ---------------- LDS-staged MFMA GEMM: h = W_split x bf16(x) ----------------
template<int CO, int CT, bool RELU_IN, bool BF16OUT>
__device__ __forceinline__ void gemm_dev(
    int bid, const float* __restrict__ X,
    const unsigned short* __restrict__ Wt_hi, const unsigned short* __restrict__ Wt_lo,
    const float* __restrict__ avs, const float* __restrict__ avd,
    void* __restrict__ Hout, float* __restrict__ as_out, float* __restrict__ ad_out,
    int N, unsigned short* smem)
{
    constexpr int CHUNKS = CO / (CT * 16);
    constexpr int HWB = CT * 4096;
    int ch, rtb;
    if (CHUNKS == 1){ ch = 0; rtb = bid; } else { ch = bid & 1; rtb = bid >> 1; }
    int c0 = ch * (CT * 16);

    {
        const char* srch = (const char*)(Wt_hi + (size_t)c0 * 128);
        const char* srcl = (const char*)(Wt_lo + (size_t)c0 * 128);
        #pragma unroll
        for (int it = 0; it < CT * 2; ++it){
            int o = (it * 256 + (int)threadIdx.x) * 16;
            const char* sp = (o < HWB) ? (srch + o) : (srcl + (o - HWB));
            u16x8 v = *(const u16x8*)sp;
            int so = o ^ (((o >> 8) & 7) << 4);
            *(u16x8*)((char*)smem + so) = v;
        }
    }
    __syncthreads();

    int wave = threadIdx.x >> 6;
    int lane = threadIdx.x & 63;
    int rt = rtb * 4 + wave;
    if (rt >= (N >> 4)) return;
    int r0 = rt << 4;
    int rl = lane & 15, g = lane >> 4;
    const float* xrow = X + (long)(r0 + rl) * 128 + g * 8;

    f32x4 acc[CT];
    #pragma unroll
    for (int t = 0; t < CT; t++) acc[t] = (f32x4)(0.f);

    int sw = (rl & 7) << 4;
    #pragma unroll
    for (int ks = 0; ks < 4; ks++){
        float4 xa = *(const float4*)(xrow + ks * 32);
        float4 xb = *(const float4*)(xrow + ks * 32 + 4);
        float xv[8] = {xa.x, xa.y, xa.z, xa.w, xb.x, xb.y, xb.z, xb.w};
        bf16x8 xbf;
        #pragma unroll
        for (int j = 0; j < 8; j++){
            float x = xv[j];
            if (RELU_IN) x = fmaxf(x, 0.f);
            xbf[j] = (short)f2bf(x);
        }
        int rbase = rl * 256 + ks * 64 + g * 16;
        #pragma unroll
        for (int t = 0; t < CT; t++){
            bf16x8 wh = *(const bf16x8*)((char*)smem + ((t * 4096 + rbase) ^ sw));
            bf16x8 wl = *(const bf16x8*)((char*)smem + ((HWB + t * 4096 + rbase) ^ sw));
            acc[t] = __builtin_amdgcn_mfma_f32_16x16x32_bf16(wh, xbf, acc[t], 0, 0, 0);
            acc[t] = __builtin_amdgcn_mfma_f32_16x16x32_bf16(wl, xbf, acc[t], 0, 0, 0);
        }
    }

    float ps = 0.f, pd = 0.f;
    #pragma unroll
    for (int t = 0; t < CT; t++){
        int c = c0 + t * 16 + 4 * g;
        float4 vs4 = *(const float4*)(avs + c);
        float4 vd4 = *(const float4*)(avd + c);
        ps += acc[t][0]*vs4.x + acc[t][1]*vs4.y + acc[t][2]*vs4.z + acc[t][3]*vs4.w;
        pd += acc[t][0]*vd4.x + acc[t][1]*vd4.y + acc[t][2]*vd4.z + acc[t][3]*vd4.w;
        long base = (long)(r0 + rl) * CO + c;
        if (BF16OUT){
            u16x4 pk;
            #pragma unroll
            for (int r = 0; r < 4; r++) pk[r] = f2bf(acc[t][r]);
            *(u16x4*)((unsigned short*)Hout + base) = pk;
        } else {
            float4 pv;
            pv.x = acc[t][0]; pv.y = acc[t][1]; pv.z = acc[t][2]; pv.w = acc[t][3];
            *(float4*)((float*)Hout + base) = pv;
        }
    }
    ps += __shfl_xor(ps, 16, 64); ps += __shfl_xor(ps, 32, 64);
    pd += __shfl_xor(pd, 16, 64); pd += __shfl_xor(pd, 32, 64);
    if (g == 0){
        unsafeAtomicAdd(as_out + r0 + rl, ps);
        unsafeAtomicAdd(ad_out + r0 + rl, pd);
    }
}

// ---------------- coarse bucket pass (LDS histogram + reserved scatter) ----------------
__device__ __forceinline__ void bucket_dev(
    int bid, const GP* __restrict__ g, int E, int Etot, int nbk, unsigned short* smem)
{
    int* spk   = (int*)smem;          // 4096 ints
    int* shist = spk + 4096;          // 256
    int* sbase = shist + 256;         // 256
    int tid = (int)threadIdx.x;
    for (int i = tid; i < nbk; i += 256) shist[i] = 0;
    __syncthreads();
    int e0 = bid * EPB;
    #pragma unroll
    for (int i = 0; i < EPB / 256; i++){
        int idx = i * 256 + tid; int e = e0 + idx;
        unsigned p = 0xFFFFFFFFu;
        if (e < Etot){
            int s, d;
            if (e < E){ s = g->src[e]; d = g->dst[e]; } else { s = e - E; d = s; }
            p = ((unsigned)s << 16) | (unsigned)d;
            atomicAdd(&shist[d >> 8], 1);
        }
        spk[idx] = (int)p;
    }
    __syncthreads();
    for (int i = tid; i < nbk; i += 256){
        sbase[i] = atomicAdd(&g->gcnt[i], shist[i]);
        shist[i] = 0;                 // reuse as fill counter
    }
    __syncthreads();
    #pragma unroll
    for (int i = 0; i < EPB / 256; i++){
        int idx = i * 256 + tid;
        unsigned p = (unsigned)spk[idx];
        if (p != 0xFFFFFFFFu){
            int d = (int)(p & 0xFFFFu); int b = d >> 8;
            int r = sbase[b] + atomicAdd(&shist[b], 1);
            if (r < CAP) g->ebuf[(size_t)b * CAP + r] = (int)p;
        }
    }
}

// ---------------- fine pass: per-bucket CSR (rowptr + sorted csrsrc) ----------------
__device__ __forceinline__ void fine_dev(int k, const GP* __restrict__ g, int N, int Etot)
{
    __shared__ int pk2[CAP];
    __shared__ int fs[256];
    __shared__ int fill[256];
    __shared__ int fh[256];
    int tid = (int)threadIdx.x;
    int cnt = min(g->gcnt[k], CAP);
    int bb  = g->gbase[k];
    for (int i = tid; i < cnt; i += 256) pk2[i] = g->ebuf[(size_t)k * CAP + i];
    fh[tid] = 0; fill[tid] = 0;
    __syncthreads();
    for (int i = tid; i < cnt; i += 256) atomicAdd(&fh[pk2[i] & 255], 1);
    __syncthreads();
    int v = fh[tid];
    fs[tid] = v;
    __syncthreads();
    #pragma unroll
    for (int off = 1; off < 256; off <<= 1){
        int t = (tid >= off) ? fs[tid - off] : 0;
        __syncthreads();
        fs[tid] += t;
        __syncthreads();
    }
    int excl = fs[tid] - v;
    __syncthreads();
    fs[tid] = excl;
    __syncthreads();
    int node = k * 256 + tid;
    if (node < N) g->rowptr[node] = bb + excl;
    if (k == 0 && tid == 0) g->rowptr[N] = Etot;
    for (int i = tid; i < cnt; i += 256){
        unsigned p = (unsigned)pk2[i];
        int f = (int)(p & 255u);
        int r = atomicAdd(&fill[f], 1);
        g->csrsrc[bb + fs[f] + r] = (int)(p >> 16);
    }
}

// ---------------- fused softmax + aggregation: one 16-lane group per node ----------------
// h is bf16 [N][CO]. 4 nodes per wave, 16 per block. Gather unrolled x4 ->
// up to 16 independent 256B/128B row reads in flight per wave.
template<int CO>
__device__ __forceinline__ void agg_dev(
    int bid, const int* __restrict__ rowptr, const int* __restrict__ csr_src,
    const float* __restrict__ as, const float* __restrict__ ad,
    const unsigned short* __restrict__ hb, const float* __restrict__ bias,
    float* __restrict__ out, int N)
{
    constexpr int ELEMS = CO / 16;         // 8 or 4 bf16 per lane
    using uvec = typename uvec_t<ELEMS>::T;
    int lane = threadIdx.x & 63;
    int wv   = threadIdx.x >> 6;
    int grp  = lane >> 4;
    int ql   = lane & 15;
    int node = bid * 16 + wv * 4 + grp;
    if (node >= N) return;
    int start = rowptr[node];
    int deg   = rowptr[node + 1] - start;
    float adv = ad[node];

    // strided edge chunks (q = 0..3): edge q*16+ql
    int   sv0 = 0, sv1 = 0, sv2 = 0, sv3 = 0;
    float ev0 = -1e30f, ev1 = -1e30f, ev2 = -1e30f, ev3 = -1e30f;
    if (ql < deg)      { sv0 = csr_src[start + ql];      ev0 = lrelu(as[sv0] + adv); }
    if (16 + ql < deg) { sv1 = csr_src[start + 16 + ql]; ev1 = lrelu(as[sv1] + adv); }
    if (32 + ql < deg) { sv2 = csr_src[start + 32 + ql]; ev2 = lrelu(as[sv2] + adv); }
    if (48 + ql < deg) { sv3 = csr_src[start + 48 + ql]; ev3 = lrelu(as[sv3] + adv); }

    float m = fmaxf(fmaxf(ev0, ev1), fmaxf(ev2, ev3));
    if (deg > 64){
        for (int j = 64 + ql; j < deg; j += 16){
            int sj = csr_src[start + j];
            m = fmaxf(m, lrelu(as[sj] + adv));
        }
    }
    #pragma unroll
    for (int off = 8; off; off >>= 1) m = fmaxf(m, __shfl_xor(m, off, 16));

    float x0 = (ql < deg)      ? __expf(ev0 - m) : 0.f;
    float x1 = (16 + ql < deg) ? __expf(ev1 - m) : 0.f;
    float x2 = (32 + ql < deg) ? __expf(ev2 - m) : 0.f;
    float x3 = (48 + ql < deg) ? __expf(ev3 - m) : 0.f;
    float sum = x0 + x1 + x2 + x3;
    if (deg > 64){
        for (int j = 64 + ql; j < deg; j += 16){
            int sj = csr_src[start + j];
            sum += __expf(lrelu(as[sj] + adv) - m);
        }
    }
    #pragma unroll
    for (int off = 8; off; off >>= 1) sum += __shfl_xor(sum, off, 16);
    float inv = 1.f / (sum + 1e-16f);
    float a0 = x0 * inv, a1 = x1 * inv, a2 = x2 * inv, a3 = x3 * inv;

    float acc[ELEMS];
    #pragma unroll
    for (int i = 0; i < ELEMS; i++) acc[i] = 0.f;

    #pragma unroll
    for (int q = 0; q < 4; q++){
        int rem = deg - q * 16;
        if (rem <= 0) break;
        int lim = rem < 16 ? rem : 16;
        float aq; int sq;
        if      (q == 0){ aq = a0; sq = sv0; }
        else if (q == 1){ aq = a1; sq = sv1; }
        else if (q == 2){ aq = a2; sq = sv2; }
        else            { aq = a3; sq = sv3; }
        int t = 0;
        for (; t + 3 < lim; t += 4){
            int   sA = __shfl(sq, t, 16),   sB = __shfl(sq, t+1, 16);
            int   sC = __shfl(sq, t+2, 16), sD = __shfl(sq, t+3, 16);
            float aA = __shfl(aq, t, 16),   aB = __shfl(aq, t+1, 16);
            float aC = __shfl(aq, t+2, 16), aD = __shfl(aq, t+3, 16);
            uvec rA = *(const uvec*)(hb + (long)sA * CO + ql * ELEMS);
            uvec rB = *(const uvec*)(hb + (long)sB * CO + ql * ELEMS);
            uvec rC = *(const uvec*)(hb + (long)sC * CO + ql * ELEMS);
            uvec rD = *(const uvec*)(hb + (long)sD * CO + ql * ELEMS);
            #pragma unroll
            for (int i = 0; i < ELEMS; i++)
                acc[i] += aA * bf2f(rA[i]) + aB * bf2f(rB[i])
                        + aC * bf2f(rC[i]) + aD * bf2f(rD[i]);
        }
        for (; t < lim; t++){
            int   sA = __shfl(sq, t, 16);
            float aA = __shfl(aq, t, 16);
            uvec rA = *(const uvec*)(hb + (long)sA * CO + ql * ELEMS);
            #pragma unroll
            for (int i = 0; i < ELEMS; i++) acc[i] += aA * bf2f(rA[i]);
        }
        if (lim < 16) break;
    }
    if (deg > 64){
        for (int j = 64; j < deg; j++){
            int sj = csr_src[start + j];               // group-uniform broadcast load
            float aj = __expf(lrelu(as[sj] + adv) - m) * inv;
            uvec rA = *(const uvec*)(hb + (long)sj * CO + ql * ELEMS);
            #pragma unroll
            for (int i = 0; i < ELEMS; i++) acc[i] += aj * bf2f(rA[i]);
        }
    }

    float* o = out + (long)node * CO + ql * ELEMS;
    #pragma unroll
    for (int i = 0; i < ELEMS; i += 4){
        float4 ov;
        ov.x = acc[i+0] + bias[ql * ELEMS + i + 0];
        ov.y = acc[i+1] + bias[ql * ELEMS + i + 1];
        ov.z = acc[i+2] + bias[ql * ELEMS + i + 2];
        ov.w = acc[i+3] + bias[ql * ELEMS + i + 3];
        *(float4*)(o + i) = ov;
    }
}

// ---------------- kernels ----------------
__global__ __launch_bounds__(BLK) void prep_k(
    const float* __restrict__ W1, const float* __restrict__ W2,
    unsigned short* __restrict__ w1h, unsigned short* __restrict__ w1l,
    unsigned short* __restrict__ w2h, unsigned short* __restrict__ w2l)
{
    int i = blockIdx.x * BLK + threadIdx.x;
    if (i < 128 * 128){
        int c = i >> 7, k = i & 127;
        float w = W1[k * 128 + c];
        unsigned short hi = f2bf(w);
        w1h[i] = hi; w1l[i] = f2bf(w - bf2f(hi));
        if (i < 64 * 128){
            float w2 = W2[k * 64 + c];
            unsigned short hi2 = f2bf(w2);
            w2h[i] = hi2; w2l[i] = f2bf(w2 - bf2f(hi2));
        }
    }
}

// kA: coarse bucket pass (both graphs) + layer-1 GEMM (both graphs)
__global__ __launch_bounds__(256, 4) void kA(
    GP a, GP b, const unsigned short* __restrict__ w1h, const unsigned short* __restrict__ w1l,
    const float* __restrict__ avs1, const float* __restrict__ avd1,
    int EB_a, int EB_b, int GB_a, int GB_b, int E, int Etot, int N, int nbk)
{
    __shared__ unsigned short smem[16384];
    int bid = blockIdx.x;
    if (bid < EB_a){ bucket_dev(bid, &a, E, Etot, nbk, smem); return; }
    bid -= EB_a;
    if (bid < EB_b){ bucket_dev(bid, &b, E, Etot, nbk, smem); return; }
    bid -= EB_b;
    if (bid < GB_a){ gemm_dev<128,4,false,true>(bid, a.X, w1h, w1l, avs1, avd1, a.h1b, a.as1, a.ad1, N, smem); return; }
    bid -= GB_a;
    if (bid < GB_b) gemm_dev<128,4,false,true>(bid, b.X, w1h, w1l, avs1, avd1, b.h1b, b.as1, b.ad1, N, smem);
}

__global__ __launch_bounds__(256) void kscan(GP a, GP b, int nbk){
    const GP* g = (blockIdx.x == 0) ? &a : &b;
    __shared__ int sh[256];
    int tid = (int)threadIdx.x;
    int v = (tid < nbk) ? g->gcnt[tid] : 0;
    sh[tid] = v;
    __syncthreads();
    #pragma unroll
    for (int off = 1; off < 256; off <<= 1){
        int t = (tid >= off) ? sh[tid - off] : 0;
        __syncthreads();
        sh[tid] += t;
        __syncthreads();
    }
    if (tid < nbk) g->gbase[tid] = sh[tid] - v;
}

__global__ __launch_bounds__(256) void kB(GP a, GP b, int nb_a, int nb_b, int N, int Etot){
    int bid = blockIdx.x; const GP* g; int k;
    if (bid < nb_a){ g = &a; k = bid; }
    else { k = bid - nb_a; if (k >= nb_b) return; g = &b; }
    fine_dev(k, g, N, Etot);
}

__global__ __launch_bounds__(256, 4) void gemm2_k(
    GP a, GP b, const unsigned short* __restrict__ w2h, const unsigned short* __restrict__ w2l,
    const float* __restrict__ avs2, const float* __restrict__ avd2, int GB_a, int GB_b, int N)
{
    __shared__ unsigned short smem[8192];
    int bid = blockIdx.x;
    if (bid < GB_a) gemm_dev<64,2,true,true>(bid, a.agg1, w2h, w2l, avs2, avd2, a.h2b, a.as2, a.ad2, N, smem);
    else { bid -= GB_a; if (bid < GB_b) gemm_dev<64,2,true,true>(bid, b.agg1, w2h, w2l, avs2, avd2, b.h2b, b.as2, b.ad2, N, smem); }
}

template<int CO>
__global__ __launch_bounds__(BLK) void agg2_k(GP a, GP b, const float* bias, int AB_a, int AB_b, int N){
    int bid = blockIdx.x; const GP* g; int lb;
    if (bid < AB_a){ g = &a; lb = bid; }
    else { lb = bid - AB_a; if (lb >= AB_b) return; g = &b; }
    const float* as; const float* ad; const unsigned short* h; float* outp;
    if constexpr (CO == 128){ as = g->as1; ad = g->ad1; h = g->h1b; outp = g->agg1; }
    else                    { as = g->as2; ad = g->ad2; h = g->h2b; outp = g->outp; }
    agg_dev<CO>(lb, g->rowptr, g->csrsrc, as, ad, h, bias, outp, N);
}

// ---------------- host ----------------
extern "C" void kernel_launch(void* const* d_in, const int* in_sizes, int n_in,
                              void* d_out, int out_size, void* d_ws, size_t ws_size,
                              hipStream_t stream)
{
    const float* fea  = (const float*)d_in[0];
    const int*   ei   = (const int*)  d_in[1];
    const float* W1   = (const float*)d_in[2];
    const float* av_s1= (const float*)d_in[3];
    const float* av_d1= (const float*)d_in[4];
    const float* b1   = (const float*)d_in[5];
    const float* W2   = (const float*)d_in[6];
    const float* av_s2= (const float*)d_in[7];
    const float* av_d2= (const float*)d_in[8];
    const float* b2   = (const float*)d_in[9];
    float* out = (float*)d_out;

    const int B = 2;
    const int N = out_size / (B * 64);          // 50000 (pack requires N <= 65536)
    const int E = in_sizes[1] / (2 * B);        // 800000
    const int Etot = E + N;
    const int nbk = (N + 255) >> 8;             // 196 coarse buckets (<=256)

    size_t pg = 256 + (size_t)nbk * CAP + (size_t)(N + 2) + (size_t)Etot
              + (size_t)N * (64 + 128 + 32);
    size_t wtf = 8192 + 8192 + 4096 + 4096;
    auto total_f = [&](int ng){ return wtf + (size_t)ng * (4 * (size_t)N + 256) + (size_t)ng * pg + 64; };
    bool fused = (ws_size >= total_f(2) * sizeof(float));
    int NG = fused ? 2 : 1;

    float* ws = (float*)d_ws;
    size_t off = 0;
    unsigned short* w1h = (unsigned short*)(ws + off); off += 8192;
    unsigned short* w1l = (unsigned short*)(ws + off); off += 8192;
    unsigned short* w2h = (unsigned short*)(ws + off); off += 4096;
    unsigned short* w2l = (unsigned short*)(ws + off); off += 4096;

    float* zbase = ws + off;
    size_t znum = (size_t)NG * (4 * (size_t)N + 256);
    off += znum;

    GP g[2];
    for (int gi = 0; gi < NG; gi++){
        GP p;
        p.as1  = zbase + (size_t)gi * (4 * (size_t)N + 256);
        p.ad1  = p.as1 + N;
        p.as2  = p.ad1 + N;
        p.ad2  = p.as2 + N;
        p.gcnt = (int*)(p.ad2 + N);
        p.gbase  = (int*)(ws + off); off += 256;
        p.ebuf   = (int*)(ws + off); off += (size_t)nbk * CAP;
        p.rowptr = (int*)(ws + off); off += (size_t)(N + 2);
        p.csrsrc = (int*)(ws + off); off += Etot;
        p.h1b  = (unsigned short*)(ws + off); off += (size_t)N * 64;
        p.agg1 = ws + off; off += (size_t)N * 128;
        p.h2b  = (unsigned short*)(ws + off); off += (size_t)N * 32;
        g[gi] = p;
    }

    const int RT  = N >> 4;
    const int GB1 = cdiv(RT, 4) * 2;
    const int GB2 = cdiv(RT, 4) * 2;
    const int EBk = cdiv(Etot, EPB);
    const int AB  = cdiv(N, 16);                // 16 nodes per block (16-lane groups)

    if (fused){
        for (int bi = 0; bi < 2; bi++){
            g[bi].src = ei + (size_t)bi * 2 * E;
            g[bi].dst = g[bi].src + E;
            g[bi].X   = fea + (size_t)bi * N * 128;
            g[bi].outp= out + (size_t)bi * N * 64;
        }
        hipMemsetAsync(zbase, 0, znum * sizeof(float), stream);
        prep_k<<<cdiv(128*128, BLK), BLK, 0, stream>>>(W1, W2, w1h, w1l, w2h, w2l);
        kA<<<2*EBk + 2*GB1, 256, 0, stream>>>(g[0], g[1], w1h, w1l, av_s1, av_d1,
                                              EBk, EBk, GB1, GB1, E, Etot, N, nbk);
        kscan<<<2, 256, 0, stream>>>(g[0], g[1], nbk);
        kB<<<2*nbk, 256, 0, stream>>>(g[0], g[1], nbk, nbk, N, Etot);
        agg2_k<128><<<2*AB, BLK, 0, stream>>>(g[0], g[1], b1, AB, AB, N);
        gemm2_k <<<2*GB2, 256, 0, stream>>>(g[0], g[1], w2h, w2l, av_s2, av_d2, GB2, GB2, N);
        agg2_k<64> <<<2*AB, BLK, 0, stream>>>(g[0], g[1], b2, AB, AB, N);
    } else {
        prep_k<<<cdiv(128*128, BLK), BLK, 0, stream>>>(W1, W2, w1h, w1l, w2h, w2l);
        for (int bi = 0; bi < B; bi++){
            GP p = g[0];
            p.src = ei + (size_t)bi * 2 * E;
            p.dst = p.src + E;
            p.X   = fea + (size_t)bi * N * 128;
            p.outp= out + (size_t)bi * N * 64;
            hipMemsetAsync(zbase, 0, znum * sizeof(float), stream);
            kA<<<EBk + GB1, 256, 0, stream>>>(p, p, w1h, w1l, av_s1, av_d1,
                                              EBk, 0, GB1, 0, E, Etot, N, nbk);
            kscan<<<1, 256, 0, stream>>>(p, p, nbk);
            kB<<<nbk, 256, 0, stream>>>(p, p, nbk, 0, N, Etot);
            agg2_k<128><<<AB, BLK, 0, stream>>>(p, p, b1, AB, 0, N);
            gemm2_k <<<GB2, 256, 0, stream>>>(p, p, w2h, w2l, av_s2, av_d2, GB2, 0, N);
            agg2_k<64> <<<AB, BLK, 0, stream>>>(p, p, b2, AB, 0, N);
        }
    }
}